// Round 6
// baseline (345.312 us; speedup 1.0000x reference)
//
#include <hip/hip_runtime.h>
#include <hip/hip_bf16.h>
#include <stdint.h>

// Problem constants
#define SEQ  2048
#define DIMM 1024
#define NH   16
#define DH   64
#define NB   4
#define MROWS (NB*SEQ)   // 8192

typedef __attribute__((ext_vector_type(8))) short bf16x8;
typedef __attribute__((ext_vector_type(4))) float f32x4;
typedef __attribute__((ext_vector_type(16))) float f32x16;

__device__ __forceinline__ unsigned short f2bf(float f) {
    union { float f; uint32_t u; } c; c.f = f;
    uint32_t r = c.u + 0x7fff + ((c.u >> 16) & 1);
    return (unsigned short)(r >> 16);
}

__device__ __forceinline__ void gload_lds16(const void* g, void* lds) {
    __builtin_amdgcn_global_load_lds(
        (const __attribute__((address_space(1))) unsigned int*)(g),
        (__attribute__((address_space(3))) unsigned int*)(lds),
        16, 0, 0);
}

// ---------------- fp32 -> bf16 elementwise convert (vectorized) -------------
__global__ __launch_bounds__(256) void k_conv_bf16(const float* __restrict__ in,
                                                   unsigned short* __restrict__ out,
                                                   int n4) {
    int i = blockIdx.x * 256 + threadIdx.x;
    if (i >= n4) return;
    float4 v = ((const float4*)in)[i];
    ushort4 o;
    o.x = f2bf(v.x); o.y = f2bf(v.y); o.z = f2bf(v.z); o.w = f2bf(v.w);
    ((ushort4*)out)[i] = o;
}

// ------------- W [K][N] fp32  ->  Wt [N][K] bf16 (tiled transpose) ----------
__global__ __launch_bounds__(256) void k_transpose(const float* __restrict__ W,
                                                   unsigned short* __restrict__ Wt,
                                                   int K, int N) {
    __shared__ unsigned short tile[32][33];
    int tn = blockIdx.x, tk = blockIdx.y;
    int lx = threadIdx.x & 31, ly = threadIdx.x >> 5;  // 32 x 8
    #pragma unroll
    for (int i = 0; i < 32; i += 8) {
        int k = tk * 32 + ly + i;
        int n = tn * 32 + lx;
        tile[ly + i][lx] = f2bf(W[(size_t)k * N + n]);
    }
    __syncthreads();
    int k2 = tk * 32 + lx;
    #pragma unroll
    for (int i = 0; i < 32; i += 8) {
        int n2 = tn * 32 + ly + i;
        Wt[(size_t)n2 * K + k2] = tile[lx][ly + i];
    }
}

// ---- V columns of qkv  ->  vt[bh][d=64][n=2048] bf16 (per-head V^T) --------
__global__ __launch_bounds__(256) void k_transpose_v(const unsigned short* __restrict__ qkv,
                                                     unsigned short* __restrict__ vt) {
    __shared__ unsigned short tile[64 * 72];
    const int nt = blockIdx.x & 31;      // kv tile of 64
    const int bh = blockIdx.x >> 5;      // 0..63
    const int b = bh >> 4, h = bh & 15;
    const int n0 = nt * 64;
    const int t = threadIdx.x;

    #pragma unroll
    for (int i = 0; i < 2; ++i) {
        int c = t + 256 * i;
        int kv = c >> 3, d0 = (c & 7) * 8;
        bf16x8 v = *(const bf16x8*)(qkv + (size_t)(b * SEQ + n0 + kv) * 3072 + 2048 + h * 64 + d0);
        *(bf16x8*)&tile[kv * 72 + d0] = v;
    }
    __syncthreads();
    #pragma unroll
    for (int i = 0; i < 2; ++i) {
        int c = t + 256 * i;
        int d = c >> 3, k0 = (c & 7) * 8;
        bf16x8 o;
        #pragma unroll
        for (int e = 0; e < 8; ++e)
            ((unsigned short*)&o)[e] = tile[(k0 + e) * 72 + d];
        *(bf16x8*)(vt + (size_t)(bh * 64 + d) * SEQ + n0 + k0) = o;
    }
}

// --------- C[M][N] = A[M][K] * Bt[N][K]^T   (bf16 in, fp32/bf16 out) --------
// SCALE_Q: multiply output cols < 1024 (the Q third of QKV) by 0.125 (exact).
template<int OUT_BF16, int SCALE_Q>
__global__ __launch_bounds__(256) void k_gemm_bt(const unsigned short* __restrict__ A,
                                                 const unsigned short* __restrict__ Bt,
                                                 void* __restrict__ Cv,
                                                 int M, int N_, int K) {
    constexpr int BM = 128, BN = 128, BK = 32;
    __shared__ unsigned short lA[BM * BK];
    __shared__ unsigned short lB[BN * BK];
    const int ntile = N_ / BN;
    const int tm = blockIdx.x / ntile;
    const int tn = blockIdx.x % ntile;
    const int t = threadIdx.x;
    const int w = t >> 6, l = t & 63;
    const int wr = w >> 1, wc = w & 1;

    const unsigned short* Abase = A + (size_t)tm * BM * K;
    const unsigned short* Bbase = Bt + (size_t)tn * BN * K;

    f32x4 acc[4][4] = {};

    for (int k0 = 0; k0 < K; k0 += BK) {
        __syncthreads();
        #pragma unroll
        for (int i = 0; i < 2; ++i) {
            int offL = (i * 4 + w) * 1024 + l * 16;
            int row = offL >> 6;
            int kb  = offL & 63;
            gload_lds16((const char*)(Abase + (size_t)row * K + k0) + kb,
                        (char*)lA + (i * 4 + w) * 1024);
            gload_lds16((const char*)(Bbase + (size_t)row * K + k0) + kb,
                        (char*)lB + (i * 4 + w) * 1024);
        }
        __syncthreads();

        bf16x8 af[4], bfv[4];
        #pragma unroll
        for (int i = 0; i < 4; ++i)
            af[i] = *(const bf16x8*)&lA[(wr * 64 + i * 16 + (l & 15)) * BK + (l >> 4) * 8];
        #pragma unroll
        for (int j = 0; j < 4; ++j)
            bfv[j] = *(const bf16x8*)&lB[(wc * 64 + j * 16 + (l & 15)) * BK + (l >> 4) * 8];
        #pragma unroll
        for (int i = 0; i < 4; ++i)
            #pragma unroll
            for (int j = 0; j < 4; ++j)
                acc[i][j] = __builtin_amdgcn_mfma_f32_16x16x32_bf16(af[i], bfv[j], acc[i][j], 0, 0, 0);
    }

    const float cs = (SCALE_Q && tn < DIMM / BN) ? 0.125f : 1.0f;
    float* Cf = (float*)Cv;
    unsigned short* Cb = (unsigned short*)Cv;
    const int row0 = tm * BM + wr * 64 + (l >> 4) * 4;
    const int col0 = tn * BN + wc * 64 + (l & 15);
    #pragma unroll
    for (int i = 0; i < 4; ++i)
        #pragma unroll
        for (int j = 0; j < 4; ++j)
            #pragma unroll
            for (int r = 0; r < 4; ++r) {
                size_t idx = (size_t)(row0 + i * 16 + r) * N_ + (col0 + j * 16);
                if (OUT_BF16) Cb[idx] = f2bf(acc[i][j][r] * cs);
                else          Cf[idx] = acc[i][j][r];
            }
}

// -------- causal flash attention (v6: swapped QK^T + paired chunks) ---------
// Wave processes q-chunk A = pair (light) and B = 15-pair (heavy): uniform
// ~34 kv-tiles/wave across the grid. K/V fragment loads shared between A,B.
// Q pre-scaled by 0.125 in the QKV GEMM. Rescale skipped when max unchanged.
__global__ __launch_bounds__(256, 2) void k_attn6(const unsigned short* __restrict__ qkv,
                                                  const unsigned short* __restrict__ vt,
                                                  unsigned short* __restrict__ out) {
    // bijective XCD swizzle: 512 blocks = 8 XCD x 64; 8 consecutive bh per XCD
    const int wid = (blockIdx.x & 7) * 64 + (blockIdx.x >> 3);
    const int bh = wid >> 3;                  // 0..63
    const int pair = wid & 7;                 // 0..7
    const int b = bh >> 4, h = bh & 15;
    const int w = threadIdx.x >> 6, l = threadIdx.x & 63;
    const int l31 = l & 31, hi = l >> 5;

    // wave-private P buffers (A,B): [32 q][64 kv] bf16, row stride 34 words
    __shared__ unsigned int Pbuf[4][2][32 * 34];
    unsigned int* PA = Pbuf[w][0];
    unsigned int* PB = Pbuf[w][1];

    const unsigned short* qp = qkv + (size_t)(b * SEQ) * 3072 + h * 64;
    const unsigned short* kp = qp + 1024;
    const unsigned short* vb = vt + (size_t)bh * 64 * SEQ;

    const int chA = pair, chB = 15 - pair;
    const int q0A = chA * 128 + w * 32, q0B = chB * 128 + w * 32;
    const int qrA = q0A + l31, qrB = q0B + l31;
    const int ntA = (q0A >> 6) + 1, ntB = (q0B >> 6) + 1;

    // Q as B-operand: col = l31 (q), k = m*16 + hi*8 + e
    bf16x8 qfA[4], qfB[4];
    #pragma unroll
    for (int m = 0; m < 4; ++m) {
        qfA[m] = *(const bf16x8*)(qp + (size_t)(q0A + l31) * 3072 + m * 16 + hi * 8);
        qfB[m] = *(const bf16x8*)(qp + (size_t)(q0B + l31) * 3072 + m * 16 + hi * 8);
    }

    f32x16 aA0 = {}, aA1 = {}, aB0 = {}, aB1 = {};
    float mA = -INFINITY, lA = 0.f, mB = -INFINITY, lB = 0.f;

    // K as A-operand: row kv = f*32 + l31, k = m*16 + hi*8 + e
    bf16x8 kf[2][4];
    #pragma unroll
    for (int f = 0; f < 2; ++f)
        #pragma unroll
        for (int m = 0; m < 4; ++m)
            kf[f][m] = *(const bf16x8*)(kp + (size_t)(f * 32 + l31) * 3072 + m * 16 + hi * 8);

    union PU { uint2 d2[2]; bf16x8 v; };

    // online softmax for one chunk; s pre-scaled (Q carries 0.125)
    auto smax = [&](f32x16& s0, f32x16& s1, float& m_run, float& l_run,
                    f32x16& o0, f32x16& o1, unsigned int* Pw,
                    int kv0, int qrow, bool msk) {
        float tmax = -1e30f;
        #pragma unroll
        for (int r = 0; r < 16; ++r) {
            const int crow = (r & 3) + 8 * (r >> 2) + 4 * hi;
            float v0 = s0[r];
            float v1 = s1[r];
            if (msk) {
                if (kv0 + crow > qrow)      v0 = -1e30f;
                if (kv0 + 32 + crow > qrow) v1 = -1e30f;
            }
            s0[r] = v0; s1[r] = v1;
            tmax = fmaxf(tmax, fmaxf(v0, v1));
        }
        tmax = fmaxf(tmax, __shfl_xor(tmax, 32));
        const bool up = __any(tmax > m_run);
        const float mnew = fmaxf(m_run, tmax);
        const float fct = __expf(m_run - mnew);
        float ps = 0.f;
        #pragma unroll
        for (int r = 0; r < 16; ++r) {
            float p0 = __expf(s0[r] - mnew);
            float p1 = __expf(s1[r] - mnew);
            s0[r] = p0; s1[r] = p1;
            ps += p0 + p1;
        }
        ps += __shfl_xor(ps, 32);
        l_run = l_run * fct + ps;
        m_run = mnew;

        // P -> wave-private LDS: s0[4g+j] -> kv = 8g + 4hi + j
        #pragma unroll
        for (int g = 0; g < 4; ++g) {
            uint2 w0, w1;
            w0.x = (unsigned int)f2bf(s0[4 * g + 0]) | ((unsigned int)f2bf(s0[4 * g + 1]) << 16);
            w0.y = (unsigned int)f2bf(s0[4 * g + 2]) | ((unsigned int)f2bf(s0[4 * g + 3]) << 16);
            w1.x = (unsigned int)f2bf(s1[4 * g + 0]) | ((unsigned int)f2bf(s1[4 * g + 1]) << 16);
            w1.y = (unsigned int)f2bf(s1[4 * g + 2]) | ((unsigned int)f2bf(s1[4 * g + 3]) << 16);
            *(uint2*)&Pw[l31 * 34 + 4 * g + 2 * hi]      = w0;
            *(uint2*)&Pw[l31 * 34 + 16 + 4 * g + 2 * hi] = w1;
        }

        // rescale O with ROW-matched factor; skip entirely if max unchanged
        if (up) {
            #pragma unroll
            for (int r = 0; r < 16; ++r) {
                const int crow = (r & 3) + 8 * (r >> 2) + 4 * hi;
                const float fr = __shfl(fct, crow);
                o0[r] *= fr;
                o1[r] *= fr;
            }
        }
    };

    for (int kt = 0; kt < ntB; ++kt) {
        const int kv0 = kt * 64;
        const bool doA = (kt < ntA);

        // QK^T swapped for both chunks, sharing K fragments
        f32x16 sA0 = {}, sA1 = {}, sB0 = {}, sB1 = {};
        __builtin_amdgcn_s_setprio(1);
        #pragma unroll
        for (int m = 0; m < 4; ++m) {
            sB0 = __builtin_amdgcn_mfma_f32_32x32x16_bf16(kf[0][m], qfB[m], sB0, 0, 0, 0);
            sB1 = __builtin_amdgcn_mfma_f32_32x32x16_bf16(kf[1][m], qfB[m], sB1, 0, 0, 0);
        }
        if (doA) {
            #pragma unroll
            for (int m = 0; m < 4; ++m) {
                sA0 = __builtin_amdgcn_mfma_f32_32x32x16_bf16(kf[0][m], qfA[m], sA0, 0, 0, 0);
                sA1 = __builtin_amdgcn_mfma_f32_32x32x16_bf16(kf[1][m], qfA[m], sA1, 0, 0, 0);
            }
        }
        __builtin_amdgcn_s_setprio(0);

        // V loads (shared by A,B PV), issued early
        bf16x8 vf0[4], vf1[4];
        #pragma unroll
        for (int m = 0; m < 4; ++m) {
            vf0[m] = *(const bf16x8*)(vb + (size_t)l31 * SEQ + kv0 + m * 16 + hi * 8);
            vf1[m] = *(const bf16x8*)(vb + (size_t)(32 + l31) * SEQ + kv0 + m * 16 + hi * 8);
        }
        // K prefetch for next tile
        const int kvn = (kt + 1 < ntB) ? kv0 + 64 : kv0;
        #pragma unroll
        for (int f = 0; f < 2; ++f)
            #pragma unroll
            for (int m = 0; m < 4; ++m)
                kf[f][m] = *(const bf16x8*)(kp + (size_t)(kvn + f * 32 + l31) * 3072 + m * 16 + hi * 8);

        // softmax B then A (A's VALU covers PB's LDS write->read latency)
        smax(sB0, sB1, mB, lB, aB0, aB1, PB, kv0, qrB, kt == ntB - 1);
        if (doA) smax(sA0, sA1, mA, lA, aA0, aA1, PA, kv0, qrA, kt == ntA - 1);

        // PV: read back A-fragments, MFMA
        bf16x8 pb[4];
        #pragma unroll
        for (int m = 0; m < 4; ++m) {
            PU pu;
            pu.d2[0] = *(const uint2*)&PB[l31 * 34 + m * 8 + 4 * hi];
            pu.d2[1] = *(const uint2*)&PB[l31 * 34 + m * 8 + 4 * hi + 2];
            pb[m] = pu.v;
        }
        __builtin_amdgcn_s_setprio(1);
        #pragma unroll
        for (int m = 0; m < 4; ++m) {
            aB0 = __builtin_amdgcn_mfma_f32_32x32x16_bf16(pb[m], vf0[m], aB0, 0, 0, 0);
            aB1 = __builtin_amdgcn_mfma_f32_32x32x16_bf16(pb[m], vf1[m], aB1, 0, 0, 0);
        }
        __builtin_amdgcn_s_setprio(0);
        if (doA) {
            bf16x8 pa[4];
            #pragma unroll
            for (int m = 0; m < 4; ++m) {
                PU pu;
                pu.d2[0] = *(const uint2*)&PA[l31 * 34 + m * 8 + 4 * hi];
                pu.d2[1] = *(const uint2*)&PA[l31 * 34 + m * 8 + 4 * hi + 2];
                pa[m] = pu.v;
            }
            __builtin_amdgcn_s_setprio(1);
            #pragma unroll
            for (int m = 0; m < 4; ++m) {
                aA0 = __builtin_amdgcn_mfma_f32_32x32x16_bf16(pa[m], vf0[m], aA0, 0, 0, 0);
                aA1 = __builtin_amdgcn_mfma_f32_32x32x16_bf16(pa[m], vf1[m], aA1, 0, 0, 0);
            }
            __builtin_amdgcn_s_setprio(0);
        }
    }

    // epilogue: O[q][d], row q = q0 + crow(r,hi), col d = 32n + l31
    unsigned short* op = out + (size_t)(b * SEQ) * DIMM + h * 64;
    #pragma unroll
    for (int r = 0; r < 16; ++r) {
        const int crow = (r & 3) + 8 * (r >> 2) + 4 * hi;
        const float invA = 1.0f / __shfl(lA, crow);
        const float invB = 1.0f / __shfl(lB, crow);
        const size_t roA = (size_t)(q0A + crow) * DIMM;
        const size_t roB = (size_t)(q0B + crow) * DIMM;
        op[roA + l31]      = f2bf(aA0[r] * invA);
        op[roA + 32 + l31] = f2bf(aA1[r] * invA);
        op[roB + l31]      = f2bf(aB0[r] * invB);
        op[roB + 32 + l31] = f2bf(aB1[r] * invB);
    }
}

// ---------------------------------------------------------------------------
extern "C" void kernel_launch(void* const* d_in, const int* in_sizes, int n_in,
                              void* d_out, int out_size, void* d_ws, size_t ws_size,
                              hipStream_t stream) {
    const float* x     = (const float*)d_in[0];   // [4,2048,1024]
    const float* w_qkv = (const float*)d_in[1];   // [1024,3072]
    const float* w_out = (const float*)d_in[2];   // [1024,1024]

    unsigned short* x_bf   = (unsigned short*)d_ws;                  // 8192*1024
    unsigned short* wqkvT  = x_bf   + (size_t)MROWS * DIMM;          // 3072*1024
    unsigned short* woutT  = wqkvT  + (size_t)3 * DIMM * DIMM;       // 1024*1024
    unsigned short* qkv_bf = woutT  + (size_t)DIMM * DIMM;           // 8192*3072
    unsigned short* aout   = qkv_bf + (size_t)MROWS * 3 * DIMM;      // 8192*1024
    unsigned short* vt     = x_bf;   // x_bf dead after QKV GEMM; alias it

    // 1. converts / transposes
    k_conv_bf16<<<(MROWS * DIMM / 4 + 255) / 256, 256, 0, stream>>>(x, x_bf, MROWS * DIMM / 4);
    dim3 g1(3 * DIMM / 32, DIMM / 32);
    k_transpose<<<g1, 256, 0, stream>>>(w_qkv, wqkvT, DIMM, 3 * DIMM);
    dim3 g2(DIMM / 32, DIMM / 32);
    k_transpose<<<g2, 256, 0, stream>>>(w_out, woutT, DIMM, DIMM);

    // 2. QKV projection (Q third pre-scaled by 0.125): -> bf16 [8192,3072]
    k_gemm_bt<1, 1><<<(MROWS / 128) * (3 * DIMM / 128), 256, 0, stream>>>(
        x_bf, wqkvT, qkv_bf, MROWS, 3 * DIMM, DIMM);

    // 3. per-head V^T (overwrites x_bf region)
    k_transpose_v<<<64 * 32, 256, 0, stream>>>(qkv_bf, vt);

    // 4. causal flash attention (paired chunks) -> bf16 [8192,1024]
    k_attn6<<<NB * NH * 8, 256, 0, stream>>>(qkv_bf, vt, aout);

    // 5. output projection: [8192,1024] x [1024,1024] -> fp32 d_out
    k_gemm_bt<0, 0><<<(MROWS / 128) * (DIMM / 128), 256, 0, stream>>>(
        aout, woutT, d_out, MROWS, DIMM, DIMM);
}

// Round 7
// 300.691 us; speedup vs baseline: 1.1484x; 1.1484x over previous
//
#include <hip/hip_runtime.h>
#include <hip/hip_bf16.h>
#include <stdint.h>

// Problem constants
#define SEQ  2048
#define DIMM 1024
#define NH   16
#define DH   64
#define NB   4
#define MROWS (NB*SEQ)   // 8192

typedef __attribute__((ext_vector_type(8))) short bf16x8;
typedef __attribute__((ext_vector_type(4))) float f32x4;
typedef __attribute__((ext_vector_type(16))) float f32x16;

__device__ __forceinline__ unsigned short f2bf(float f) {
    union { float f; uint32_t u; } c; c.f = f;
    uint32_t r = c.u + 0x7fff + ((c.u >> 16) & 1);
    return (unsigned short)(r >> 16);
}

__device__ __forceinline__ void gload_lds16(const void* g, void* lds) {
    __builtin_amdgcn_global_load_lds(
        (const __attribute__((address_space(1))) unsigned int*)(g),
        (__attribute__((address_space(3))) unsigned int*)(lds),
        16, 0, 0);
}

// ---------------- fp32 -> bf16 elementwise convert (vectorized) -------------
__global__ __launch_bounds__(256) void k_conv_bf16(const float* __restrict__ in,
                                                   unsigned short* __restrict__ out,
                                                   int n4) {
    int i = blockIdx.x * 256 + threadIdx.x;
    if (i >= n4) return;
    float4 v = ((const float4*)in)[i];
    ushort4 o;
    o.x = f2bf(v.x); o.y = f2bf(v.y); o.z = f2bf(v.z); o.w = f2bf(v.w);
    ((ushort4*)out)[i] = o;
}

// ------------- W [K][N] fp32  ->  Wt [N][K] bf16 (tiled transpose) ----------
__global__ __launch_bounds__(256) void k_transpose(const float* __restrict__ W,
                                                   unsigned short* __restrict__ Wt,
                                                   int K, int N) {
    __shared__ unsigned short tile[32][33];
    int tn = blockIdx.x, tk = blockIdx.y;
    int lx = threadIdx.x & 31, ly = threadIdx.x >> 5;  // 32 x 8
    #pragma unroll
    for (int i = 0; i < 32; i += 8) {
        int k = tk * 32 + ly + i;
        int n = tn * 32 + lx;
        tile[ly + i][lx] = f2bf(W[(size_t)k * N + n]);
    }
    __syncthreads();
    int k2 = tk * 32 + lx;
    #pragma unroll
    for (int i = 0; i < 32; i += 8) {
        int n2 = tn * 32 + ly + i;
        Wt[(size_t)n2 * K + k2] = tile[lx][ly + i];
    }
}

// ---- V columns of qkv  ->  vt[bh][d=64][n=2048] bf16 (per-head V^T) --------
__global__ __launch_bounds__(256) void k_transpose_v(const unsigned short* __restrict__ qkv,
                                                     unsigned short* __restrict__ vt) {
    __shared__ unsigned short tile[64 * 72];
    const int nt = blockIdx.x & 31;      // kv tile of 64
    const int bh = blockIdx.x >> 5;      // 0..63
    const int b = bh >> 4, h = bh & 15;
    const int n0 = nt * 64;
    const int t = threadIdx.x;

    #pragma unroll
    for (int i = 0; i < 2; ++i) {
        int c = t + 256 * i;
        int kv = c >> 3, d0 = (c & 7) * 8;
        bf16x8 v = *(const bf16x8*)(qkv + (size_t)(b * SEQ + n0 + kv) * 3072 + 2048 + h * 64 + d0);
        *(bf16x8*)&tile[kv * 72 + d0] = v;
    }
    __syncthreads();
    #pragma unroll
    for (int i = 0; i < 2; ++i) {
        int c = t + 256 * i;
        int d = c >> 3, k0 = (c & 7) * 8;
        bf16x8 o;
        #pragma unroll
        for (int e = 0; e < 8; ++e)
            ((unsigned short*)&o)[e] = tile[(k0 + e) * 72 + d];
        *(bf16x8*)(vt + (size_t)(bh * 64 + d) * SEQ + n0 + k0) = o;
    }
}

// --------- C[M][N] = A[M][K] * Bt[N][K]^T   (bf16 in, fp32/bf16 out) --------
// SCALE_Q: multiply output cols < 1024 (the Q third of QKV) by 0.125 (exact).
template<int OUT_BF16, int SCALE_Q>
__global__ __launch_bounds__(256) void k_gemm_bt(const unsigned short* __restrict__ A,
                                                 const unsigned short* __restrict__ Bt,
                                                 void* __restrict__ Cv,
                                                 int M, int N_, int K) {
    constexpr int BM = 128, BN = 128, BK = 32;
    __shared__ unsigned short lA[BM * BK];
    __shared__ unsigned short lB[BN * BK];
    const int ntile = N_ / BN;
    const int tm = blockIdx.x / ntile;
    const int tn = blockIdx.x % ntile;
    const int t = threadIdx.x;
    const int w = t >> 6, l = t & 63;
    const int wr = w >> 1, wc = w & 1;

    const unsigned short* Abase = A + (size_t)tm * BM * K;
    const unsigned short* Bbase = Bt + (size_t)tn * BN * K;

    f32x4 acc[4][4] = {};

    for (int k0 = 0; k0 < K; k0 += BK) {
        __syncthreads();
        #pragma unroll
        for (int i = 0; i < 2; ++i) {
            int offL = (i * 4 + w) * 1024 + l * 16;
            int row = offL >> 6;
            int kb  = offL & 63;
            gload_lds16((const char*)(Abase + (size_t)row * K + k0) + kb,
                        (char*)lA + (i * 4 + w) * 1024);
            gload_lds16((const char*)(Bbase + (size_t)row * K + k0) + kb,
                        (char*)lB + (i * 4 + w) * 1024);
        }
        __syncthreads();

        bf16x8 af[4], bfv[4];
        #pragma unroll
        for (int i = 0; i < 4; ++i)
            af[i] = *(const bf16x8*)&lA[(wr * 64 + i * 16 + (l & 15)) * BK + (l >> 4) * 8];
        #pragma unroll
        for (int j = 0; j < 4; ++j)
            bfv[j] = *(const bf16x8*)&lB[(wc * 64 + j * 16 + (l & 15)) * BK + (l >> 4) * 8];
        #pragma unroll
        for (int i = 0; i < 4; ++i)
            #pragma unroll
            for (int j = 0; j < 4; ++j)
                acc[i][j] = __builtin_amdgcn_mfma_f32_16x16x32_bf16(af[i], bfv[j], acc[i][j], 0, 0, 0);
    }

    const float cs = (SCALE_Q && tn < DIMM / BN) ? 0.125f : 1.0f;
    float* Cf = (float*)Cv;
    unsigned short* Cb = (unsigned short*)Cv;
    const int row0 = tm * BM + wr * 64 + (l >> 4) * 4;
    const int col0 = tn * BN + wc * 64 + (l & 15);
    #pragma unroll
    for (int i = 0; i < 4; ++i)
        #pragma unroll
        for (int j = 0; j < 4; ++j)
            #pragma unroll
            for (int r = 0; r < 4; ++r) {
                size_t idx = (size_t)(row0 + i * 16 + r) * N_ + (col0 + j * 16);
                if (OUT_BF16) Cb[idx] = f2bf(acc[i][j][r] * cs);
                else          Cf[idx] = acc[i][j][r];
            }
}

// ----- causal flash attention (v7: swapped QK^T, wave-level chunk pairing) --
// Block = 8 waves: waves 0-3 -> heavy chunk (15-p), waves 4-7 -> light chunk p.
// Each wave runs the v5 single-chunk loop (no extra register state, no spill).
// Per-block work uniform (~34 kv-tiles); 512 blocks = 2/CU exactly.
__global__ __launch_bounds__(512, 4) void k_attn7(const unsigned short* __restrict__ qkv,
                                                  const unsigned short* __restrict__ vt,
                                                  unsigned short* __restrict__ out) {
    // bijective XCD swizzle: 512 blocks = 8 XCD x 64; 8 consecutive bh per XCD
    const int wid = (blockIdx.x & 7) * 64 + (blockIdx.x >> 3);
    const int bh = wid >> 3;                  // 0..63
    const int pair = wid & 7;                 // 0..7
    const int b = bh >> 4, h = bh & 15;
    const int w8 = threadIdx.x >> 6, l = threadIdx.x & 63;
    const int l31 = l & 31, hi = l >> 5;

    // per-wave P buffer: [32 q][64 kv] bf16, row stride 34 u32 words
    __shared__ unsigned int Pbuf[8][32 * 34];
    unsigned int* Pw = Pbuf[w8];

    const unsigned short* qp = qkv + (size_t)(b * SEQ) * 3072 + h * 64;
    const unsigned short* kp = qp + 1024;
    const unsigned short* vb = vt + (size_t)bh * 64 * SEQ;

    const int chunk = (w8 < 4) ? (15 - pair) : pair;   // heavy : light
    const int q0w = chunk * 128 + (w8 & 3) * 32;       // wave's first q row
    const int qrow = q0w + l31;                        // this lane's q row
    const int nt = (q0w >> 6) + 1;                     // kv-tile trip count

    // Q as B-operand: col = l31 (q), k = m*16 + hi*8 + e  (pre-scaled by 1/8)
    bf16x8 qf[4];
    #pragma unroll
    for (int m = 0; m < 4; ++m)
        qf[m] = *(const bf16x8*)(qp + (size_t)(q0w + l31) * 3072 + m * 16 + hi * 8);

    f32x16 accO0 = {}, accO1 = {};
    float m_run = -INFINITY, l_run = 0.f;

    // K as A-operand: row kv = f*32 + l31, k = m*16 + hi*8 + e
    bf16x8 kf[2][4];
    #pragma unroll
    for (int f = 0; f < 2; ++f)
        #pragma unroll
        for (int m = 0; m < 4; ++m)
            kf[f][m] = *(const bf16x8*)(kp + (size_t)(f * 32 + l31) * 3072 + m * 16 + hi * 8);

    union PU { uint2 d2[2]; bf16x8 v; };

    for (int kt = 0; kt < nt; ++kt) {
        const int kv0 = kt * 64;
        const bool msk = (kt == nt - 1);

        // QK^T swapped -> S^T: lane holds q=l31, kv = f*32 + crow(r,hi)
        f32x16 s0 = {}, s1 = {};
        __builtin_amdgcn_s_setprio(1);
        #pragma unroll
        for (int m = 0; m < 4; ++m) {
            s0 = __builtin_amdgcn_mfma_f32_32x32x16_bf16(kf[0][m], qf[m], s0, 0, 0, 0);
            s1 = __builtin_amdgcn_mfma_f32_32x32x16_bf16(kf[1][m], qf[m], s1, 0, 0, 0);
        }
        __builtin_amdgcn_s_setprio(0);

        // V loads issued early (latency hides under softmax)
        bf16x8 vf0[4], vf1[4];
        #pragma unroll
        for (int m = 0; m < 4; ++m) {
            vf0[m] = *(const bf16x8*)(vb + (size_t)l31 * SEQ + kv0 + m * 16 + hi * 8);
            vf1[m] = *(const bf16x8*)(vb + (size_t)(32 + l31) * SEQ + kv0 + m * 16 + hi * 8);
        }
        // K prefetch for next tile (kf dead after QK^T above)
        const int kvn = (kt + 1 < nt) ? kv0 + 64 : kv0;
        #pragma unroll
        for (int f = 0; f < 2; ++f)
            #pragma unroll
            for (int m = 0; m < 4; ++m)
                kf[f][m] = *(const bf16x8*)(kp + (size_t)(kvn + f * 32 + l31) * 3072 + m * 16 + hi * 8);

        // ---- in-lane online softmax (lane owns q row = l31) ----
        float tmax = -1e30f;
        #pragma unroll
        for (int r = 0; r < 16; ++r) {
            const int crow = (r & 3) + 8 * (r >> 2) + 4 * hi;
            float v0 = s0[r];
            float v1 = s1[r];
            if (msk) {
                if (kv0 + crow > qrow)      v0 = -1e30f;
                if (kv0 + 32 + crow > qrow) v1 = -1e30f;
            }
            s0[r] = v0; s1[r] = v1;
            tmax = fmaxf(tmax, fmaxf(v0, v1));
        }
        tmax = fmaxf(tmax, __shfl_xor(tmax, 32));      // other kv half
        const bool up = __any(tmax > m_run);
        const float mnew = fmaxf(m_run, tmax);
        const float fct = __expf(m_run - mnew);
        float ps = 0.f;
        #pragma unroll
        for (int r = 0; r < 16; ++r) {
            float p0 = __expf(s0[r] - mnew);
            float p1 = __expf(s1[r] - mnew);
            s0[r] = p0; s1[r] = p1;
            ps += p0 + p1;
        }
        ps += __shfl_xor(ps, 32);
        l_run = l_run * fct + ps;
        m_run = mnew;

        // ---- P -> wave-private LDS (q-row l31, packed kv pairs) ----
        // s0[4g+j] -> kv = 8g + 4hi + j  (consecutive per g)
        #pragma unroll
        for (int g = 0; g < 4; ++g) {
            uint2 w0, w1;
            w0.x = (unsigned int)f2bf(s0[4 * g + 0]) | ((unsigned int)f2bf(s0[4 * g + 1]) << 16);
            w0.y = (unsigned int)f2bf(s0[4 * g + 2]) | ((unsigned int)f2bf(s0[4 * g + 3]) << 16);
            w1.x = (unsigned int)f2bf(s1[4 * g + 0]) | ((unsigned int)f2bf(s1[4 * g + 1]) << 16);
            w1.y = (unsigned int)f2bf(s1[4 * g + 2]) | ((unsigned int)f2bf(s1[4 * g + 3]) << 16);
            *(uint2*)&Pw[l31 * 34 + 4 * g + 2 * hi]      = w0;   // kv 0..31 half
            *(uint2*)&Pw[l31 * 34 + 16 + 4 * g + 2 * hi] = w1;   // kv 32..63 half
        }

        // ---- rescale O with ROW-matched factor; skip if max unchanged ----
        if (up) {
            #pragma unroll
            for (int r = 0; r < 16; ++r) {
                const int crow = (r & 3) + 8 * (r >> 2) + 4 * hi;
                const float fr = __shfl(fct, crow);   // lane crow holds row crow's factor
                accO0[r] *= fr;
                accO1[r] *= fr;
            }
        }

        // ---- read back PV A-fragments: P[q=l31][kv = m*16 + hi*8 + 0..7] ----
        bf16x8 pa[4];
        #pragma unroll
        for (int m = 0; m < 4; ++m) {
            PU pu;
            pu.d2[0] = *(const uint2*)&Pw[l31 * 34 + m * 8 + 4 * hi];
            pu.d2[1] = *(const uint2*)&Pw[l31 * 34 + m * 8 + 4 * hi + 2];
            pa[m] = pu.v;
        }

        __builtin_amdgcn_s_setprio(1);
        #pragma unroll
        for (int m = 0; m < 4; ++m) {
            accO0 = __builtin_amdgcn_mfma_f32_32x32x16_bf16(pa[m], vf0[m], accO0, 0, 0, 0);
            accO1 = __builtin_amdgcn_mfma_f32_32x32x16_bf16(pa[m], vf1[m], accO1, 0, 0, 0);
        }
        __builtin_amdgcn_s_setprio(0);
    }

    // epilogue: O[q][d], row q = q0w + crow(r,hi), col d = 32n + l31
    unsigned short* op = out + (size_t)(b * SEQ) * DIMM + h * 64;
    #pragma unroll
    for (int r = 0; r < 16; ++r) {
        const int crow = (r & 3) + 8 * (r >> 2) + 4 * hi;
        float inv = 1.0f / __shfl(l_run, crow);   // lane crow holds that row's sum
        const size_t rowoff = (size_t)(q0w + crow) * DIMM;
        op[rowoff + l31]      = f2bf(accO0[r] * inv);
        op[rowoff + 32 + l31] = f2bf(accO1[r] * inv);
    }
}

// ---------------------------------------------------------------------------
extern "C" void kernel_launch(void* const* d_in, const int* in_sizes, int n_in,
                              void* d_out, int out_size, void* d_ws, size_t ws_size,
                              hipStream_t stream) {
    const float* x     = (const float*)d_in[0];   // [4,2048,1024]
    const float* w_qkv = (const float*)d_in[1];   // [1024,3072]
    const float* w_out = (const float*)d_in[2];   // [1024,1024]

    unsigned short* x_bf   = (unsigned short*)d_ws;                  // 8192*1024
    unsigned short* wqkvT  = x_bf   + (size_t)MROWS * DIMM;          // 3072*1024
    unsigned short* woutT  = wqkvT  + (size_t)3 * DIMM * DIMM;       // 1024*1024
    unsigned short* qkv_bf = woutT  + (size_t)DIMM * DIMM;           // 8192*3072
    unsigned short* aout   = qkv_bf + (size_t)MROWS * 3 * DIMM;      // 8192*1024
    unsigned short* vt     = x_bf;   // x_bf dead after QKV GEMM; alias it

    // 1. converts / transposes
    k_conv_bf16<<<(MROWS * DIMM / 4 + 255) / 256, 256, 0, stream>>>(x, x_bf, MROWS * DIMM / 4);
    dim3 g1(3 * DIMM / 32, DIMM / 32);
    k_transpose<<<g1, 256, 0, stream>>>(w_qkv, wqkvT, DIMM, 3 * DIMM);
    dim3 g2(DIMM / 32, DIMM / 32);
    k_transpose<<<g2, 256, 0, stream>>>(w_out, woutT, DIMM, DIMM);

    // 2. QKV projection (Q third pre-scaled by 0.125): -> bf16 [8192,3072]
    k_gemm_bt<1, 1><<<(MROWS / 128) * (3 * DIMM / 128), 256, 0, stream>>>(
        x_bf, wqkvT, qkv_bf, MROWS, 3 * DIMM, DIMM);

    // 3. per-head V^T (overwrites x_bf region)
    k_transpose_v<<<64 * 32, 256, 0, stream>>>(qkv_bf, vt);

    // 4. causal flash attention (wave-level chunk pairing) -> bf16 [8192,1024]
    k_attn7<<<NB * NH * 8, 512, 0, stream>>>(qkv_bf, vt, aout);

    // 5. output projection: [8192,1024] x [1024,1024] -> fp32 d_out
    k_gemm_bt<0, 0><<<(MROWS / 128) * (DIMM / 128), 256, 0, stream>>>(
        aout, woutT, d_out, MROWS, DIMM, DIMM);
}

// Round 8
// 250.082 us; speedup vs baseline: 1.3808x; 1.2024x over previous
//
#include <hip/hip_runtime.h>
#include <hip/hip_bf16.h>
#include <stdint.h>

// Problem constants
#define SEQ  2048
#define DIMM 1024
#define NH   16
#define DH   64
#define NB   4
#define MROWS (NB*SEQ)   // 8192

typedef __attribute__((ext_vector_type(8))) short bf16x8;
typedef __attribute__((ext_vector_type(4))) float f32x4;
typedef __attribute__((ext_vector_type(16))) float f32x16;

__device__ __forceinline__ unsigned short f2bf(float f) {
    union { float f; uint32_t u; } c; c.f = f;
    uint32_t r = c.u + 0x7fff + ((c.u >> 16) & 1);
    return (unsigned short)(r >> 16);
}

__device__ __forceinline__ void gload_lds16(const void* g, void* lds) {
    __builtin_amdgcn_global_load_lds(
        (const __attribute__((address_space(1))) unsigned int*)(g),
        (__attribute__((address_space(3))) unsigned int*)(lds),
        16, 0, 0);
}

// ---------------- fp32 -> bf16 elementwise convert (vectorized) -------------
__global__ __launch_bounds__(256) void k_conv_bf16(const float* __restrict__ in,
                                                   unsigned short* __restrict__ out,
                                                   int n4) {
    int i = blockIdx.x * 256 + threadIdx.x;
    if (i >= n4) return;
    float4 v = ((const float4*)in)[i];
    ushort4 o;
    o.x = f2bf(v.x); o.y = f2bf(v.y); o.z = f2bf(v.z); o.w = f2bf(v.w);
    ((ushort4*)out)[i] = o;
}

// ------------- W [K][N] fp32  ->  Wt [N][K] bf16 (tiled transpose) ----------
__global__ __launch_bounds__(256) void k_transpose(const float* __restrict__ W,
                                                   unsigned short* __restrict__ Wt,
                                                   int K, int N) {
    __shared__ unsigned short tile[32][33];
    int tn = blockIdx.x, tk = blockIdx.y;
    int lx = threadIdx.x & 31, ly = threadIdx.x >> 5;  // 32 x 8
    #pragma unroll
    for (int i = 0; i < 32; i += 8) {
        int k = tk * 32 + ly + i;
        int n = tn * 32 + lx;
        tile[ly + i][lx] = f2bf(W[(size_t)k * N + n]);
    }
    __syncthreads();
    int k2 = tk * 32 + lx;
    #pragma unroll
    for (int i = 0; i < 32; i += 8) {
        int n2 = tn * 32 + ly + i;
        Wt[(size_t)n2 * K + k2] = tile[lx][ly + i];
    }
}

// ---- V columns of qkv  ->  vt[bh][d=64][n=2048] bf16 (per-head V^T) --------
__global__ __launch_bounds__(256) void k_transpose_v(const unsigned short* __restrict__ qkv,
                                                     unsigned short* __restrict__ vt) {
    __shared__ unsigned short tile[64 * 72];
    const int nt = blockIdx.x & 31;      // kv tile of 64
    const int bh = blockIdx.x >> 5;      // 0..63
    const int b = bh >> 4, h = bh & 15;
    const int n0 = nt * 64;
    const int t = threadIdx.x;

    #pragma unroll
    for (int i = 0; i < 2; ++i) {
        int c = t + 256 * i;
        int kv = c >> 3, d0 = (c & 7) * 8;
        bf16x8 v = *(const bf16x8*)(qkv + (size_t)(b * SEQ + n0 + kv) * 3072 + 2048 + h * 64 + d0);
        *(bf16x8*)&tile[kv * 72 + d0] = v;
    }
    __syncthreads();
    #pragma unroll
    for (int i = 0; i < 2; ++i) {
        int c = t + 256 * i;
        int d = c >> 3, k0 = (c & 7) * 8;
        bf16x8 o;
        #pragma unroll
        for (int e = 0; e < 8; ++e)
            ((unsigned short*)&o)[e] = tile[(k0 + e) * 72 + d];
        *(bf16x8*)(vt + (size_t)(bh * 64 + d) * SEQ + n0 + k0) = o;
    }
}

// --------- C[M][N] = A[M][K] * Bt[N][K]^T   (bf16 in, fp32/bf16 out) --------
// SCALE_Q: multiply output cols < 1024 (the Q third of QKV) by 0.125 (exact).
template<int OUT_BF16, int SCALE_Q>
__global__ __launch_bounds__(256) void k_gemm_bt(const unsigned short* __restrict__ A,
                                                 const unsigned short* __restrict__ Bt,
                                                 void* __restrict__ Cv,
                                                 int M, int N_, int K) {
    constexpr int BM = 128, BN = 128, BK = 32;
    __shared__ unsigned short lA[BM * BK];
    __shared__ unsigned short lB[BN * BK];
    const int ntile = N_ / BN;
    const int tm = blockIdx.x / ntile;
    const int tn = blockIdx.x % ntile;
    const int t = threadIdx.x;
    const int w = t >> 6, l = t & 63;
    const int wr = w >> 1, wc = w & 1;

    const unsigned short* Abase = A + (size_t)tm * BM * K;
    const unsigned short* Bbase = Bt + (size_t)tn * BN * K;

    f32x4 acc[4][4] = {};

    for (int k0 = 0; k0 < K; k0 += BK) {
        __syncthreads();
        #pragma unroll
        for (int i = 0; i < 2; ++i) {
            int offL = (i * 4 + w) * 1024 + l * 16;
            int row = offL >> 6;
            int kb  = offL & 63;
            gload_lds16((const char*)(Abase + (size_t)row * K + k0) + kb,
                        (char*)lA + (i * 4 + w) * 1024);
            gload_lds16((const char*)(Bbase + (size_t)row * K + k0) + kb,
                        (char*)lB + (i * 4 + w) * 1024);
        }
        __syncthreads();

        bf16x8 af[4], bfv[4];
        #pragma unroll
        for (int i = 0; i < 4; ++i)
            af[i] = *(const bf16x8*)&lA[(wr * 64 + i * 16 + (l & 15)) * BK + (l >> 4) * 8];
        #pragma unroll
        for (int j = 0; j < 4; ++j)
            bfv[j] = *(const bf16x8*)&lB[(wc * 64 + j * 16 + (l & 15)) * BK + (l >> 4) * 8];
        #pragma unroll
        for (int i = 0; i < 4; ++i)
            #pragma unroll
            for (int j = 0; j < 4; ++j)
                acc[i][j] = __builtin_amdgcn_mfma_f32_16x16x32_bf16(af[i], bfv[j], acc[i][j], 0, 0, 0);
    }

    const float cs = (SCALE_Q && tn < DIMM / BN) ? 0.125f : 1.0f;
    float* Cf = (float*)Cv;
    unsigned short* Cb = (unsigned short*)Cv;
    const int row0 = tm * BM + wr * 64 + (l >> 4) * 4;
    const int col0 = tn * BN + wc * 64 + (l & 15);
    #pragma unroll
    for (int i = 0; i < 4; ++i)
        #pragma unroll
        for (int j = 0; j < 4; ++j)
            #pragma unroll
            for (int r = 0; r < 4; ++r) {
                size_t idx = (size_t)(row0 + i * 16 + r) * N_ + (col0 + j * 16);
                if (OUT_BF16) Cb[idx] = f2bf(acc[i][j][r] * cs);
                else          Cf[idx] = acc[i][j][r];
            }
}

// -- causal flash attention (v8: swapped QK^T, sequential chunk pairing) -----
// Each wave runs TWO chunks back-to-back: heavy (15-p) then light (p), with
// full register reuse (same live state as the v5 loop -> no spills). Per-wave
// work is uniform (~33 kv-tiles) by construction. 512 blocks x 4 waves.
__global__ __launch_bounds__(256, 2) void k_attn8(const unsigned short* __restrict__ qkv,
                                                  const unsigned short* __restrict__ vt,
                                                  unsigned short* __restrict__ out) {
    // bijective XCD swizzle: 512 blocks = 8 XCD x 64; 8 consecutive bh per XCD
    const int wid = (blockIdx.x & 7) * 64 + (blockIdx.x >> 3);
    const int bh = wid >> 3;                  // 0..63
    const int pair = wid & 7;                 // 0..7
    const int b = bh >> 4, h = bh & 15;
    const int w = threadIdx.x >> 6, l = threadIdx.x & 63;
    const int l31 = l & 31, hi = l >> 5;

    // per-wave P buffer: [32 q][64 kv] bf16, row stride 34 u32 words
    __shared__ unsigned int Pbuf[4][32 * 34];
    unsigned int* Pw = Pbuf[w];

    const unsigned short* qp = qkv + (size_t)(b * SEQ) * 3072 + h * 64;
    const unsigned short* kp = qp + 1024;
    const unsigned short* vb = vt + (size_t)bh * 64 * SEQ;
    unsigned short* op = out + (size_t)(b * SEQ) * DIMM + h * 64;

    union PU { uint2 d2[2]; bf16x8 v; };

    for (int ci = 0; ci < 2; ++ci) {
        const int chunk = ci ? pair : 15 - pair;       // heavy first, then light
        const int q0w = chunk * 128 + w * 32;          // wave's first q row
        const int qrow = q0w + l31;                    // this lane's q row
        const int nt = (q0w >> 6) + 1;                 // kv-tile trip count

        // Q as B-operand: col = l31 (q), k = m*16 + hi*8 + e  (pre-scaled 1/8)
        bf16x8 qf[4];
        #pragma unroll
        for (int m = 0; m < 4; ++m)
            qf[m] = *(const bf16x8*)(qp + (size_t)(q0w + l31) * 3072 + m * 16 + hi * 8);

        f32x16 accO0 = {}, accO1 = {};
        float m_run = -INFINITY, l_run = 0.f;

        // K as A-operand: row kv = f*32 + l31, k = m*16 + hi*8 + e
        bf16x8 kf[2][4];
        #pragma unroll
        for (int f = 0; f < 2; ++f)
            #pragma unroll
            for (int m = 0; m < 4; ++m)
                kf[f][m] = *(const bf16x8*)(kp + (size_t)(f * 32 + l31) * 3072 + m * 16 + hi * 8);

        for (int kt = 0; kt < nt; ++kt) {
            const int kv0 = kt * 64;
            const bool msk = (kt == nt - 1);

            // QK^T swapped -> S^T: lane holds q=l31, kv = f*32 + crow(r,hi)
            f32x16 s0 = {}, s1 = {};
            __builtin_amdgcn_s_setprio(1);
            #pragma unroll
            for (int m = 0; m < 4; ++m) {
                s0 = __builtin_amdgcn_mfma_f32_32x32x16_bf16(kf[0][m], qf[m], s0, 0, 0, 0);
                s1 = __builtin_amdgcn_mfma_f32_32x32x16_bf16(kf[1][m], qf[m], s1, 0, 0, 0);
            }
            __builtin_amdgcn_s_setprio(0);

            // V loads issued early (latency hides under softmax)
            bf16x8 vf0[4], vf1[4];
            #pragma unroll
            for (int m = 0; m < 4; ++m) {
                vf0[m] = *(const bf16x8*)(vb + (size_t)l31 * SEQ + kv0 + m * 16 + hi * 8);
                vf1[m] = *(const bf16x8*)(vb + (size_t)(32 + l31) * SEQ + kv0 + m * 16 + hi * 8);
            }
            // K prefetch for next tile (kf dead after QK^T above)
            const int kvn = (kt + 1 < nt) ? kv0 + 64 : kv0;
            #pragma unroll
            for (int f = 0; f < 2; ++f)
                #pragma unroll
                for (int m = 0; m < 4; ++m)
                    kf[f][m] = *(const bf16x8*)(kp + (size_t)(kvn + f * 32 + l31) * 3072 + m * 16 + hi * 8);

            // ---- in-lane online softmax (lane owns q row = l31) ----
            float tmax = -1e30f;
            #pragma unroll
            for (int r = 0; r < 16; ++r) {
                const int crow = (r & 3) + 8 * (r >> 2) + 4 * hi;
                float v0 = s0[r];
                float v1 = s1[r];
                if (msk) {
                    if (kv0 + crow > qrow)      v0 = -1e30f;
                    if (kv0 + 32 + crow > qrow) v1 = -1e30f;
                }
                s0[r] = v0; s1[r] = v1;
                tmax = fmaxf(tmax, fmaxf(v0, v1));
            }
            tmax = fmaxf(tmax, __shfl_xor(tmax, 32));      // other kv half
            const bool up = __any(tmax > m_run);
            const float mnew = fmaxf(m_run, tmax);
            const float fct = __expf(m_run - mnew);
            float ps = 0.f;
            #pragma unroll
            for (int r = 0; r < 16; ++r) {
                float p0 = __expf(s0[r] - mnew);
                float p1 = __expf(s1[r] - mnew);
                s0[r] = p0; s1[r] = p1;
                ps += p0 + p1;
            }
            ps += __shfl_xor(ps, 32);
            l_run = l_run * fct + ps;
            m_run = mnew;

            // ---- P -> wave-private LDS (q-row l31, packed kv pairs) ----
            // s0[4g+j] -> kv = 8g + 4hi + j  (consecutive per g)
            #pragma unroll
            for (int g = 0; g < 4; ++g) {
                uint2 w0, w1;
                w0.x = (unsigned int)f2bf(s0[4 * g + 0]) | ((unsigned int)f2bf(s0[4 * g + 1]) << 16);
                w0.y = (unsigned int)f2bf(s0[4 * g + 2]) | ((unsigned int)f2bf(s0[4 * g + 3]) << 16);
                w1.x = (unsigned int)f2bf(s1[4 * g + 0]) | ((unsigned int)f2bf(s1[4 * g + 1]) << 16);
                w1.y = (unsigned int)f2bf(s1[4 * g + 2]) | ((unsigned int)f2bf(s1[4 * g + 3]) << 16);
                *(uint2*)&Pw[l31 * 34 + 4 * g + 2 * hi]      = w0;   // kv 0..31 half
                *(uint2*)&Pw[l31 * 34 + 16 + 4 * g + 2 * hi] = w1;   // kv 32..63 half
            }

            // ---- rescale O with ROW-matched factor; skip if max unchanged ----
            if (up) {
                #pragma unroll
                for (int r = 0; r < 16; ++r) {
                    const int crow = (r & 3) + 8 * (r >> 2) + 4 * hi;
                    const float fr = __shfl(fct, crow);
                    accO0[r] *= fr;
                    accO1[r] *= fr;
                }
            }

            // ---- read back PV A-fragments: P[q=l31][kv = m*16 + hi*8 + 0..7] --
            bf16x8 pa[4];
            #pragma unroll
            for (int m = 0; m < 4; ++m) {
                PU pu;
                pu.d2[0] = *(const uint2*)&Pw[l31 * 34 + m * 8 + 4 * hi];
                pu.d2[1] = *(const uint2*)&Pw[l31 * 34 + m * 8 + 4 * hi + 2];
                pa[m] = pu.v;
            }

            __builtin_amdgcn_s_setprio(1);
            #pragma unroll
            for (int m = 0; m < 4; ++m) {
                accO0 = __builtin_amdgcn_mfma_f32_32x32x16_bf16(pa[m], vf0[m], accO0, 0, 0, 0);
                accO1 = __builtin_amdgcn_mfma_f32_32x32x16_bf16(pa[m], vf1[m], accO1, 0, 0, 0);
            }
            __builtin_amdgcn_s_setprio(0);
        }

        // epilogue: O[q][d], row q = q0w + crow(r,hi), col d = 32n + l31
        #pragma unroll
        for (int r = 0; r < 16; ++r) {
            const int crow = (r & 3) + 8 * (r >> 2) + 4 * hi;
            float inv = 1.0f / __shfl(l_run, crow);   // lane crow holds that row's sum
            const size_t rowoff = (size_t)(q0w + crow) * DIMM;
            op[rowoff + l31]      = f2bf(accO0[r] * inv);
            op[rowoff + 32 + l31] = f2bf(accO1[r] * inv);
        }
    }
}

// ---------------------------------------------------------------------------
extern "C" void kernel_launch(void* const* d_in, const int* in_sizes, int n_in,
                              void* d_out, int out_size, void* d_ws, size_t ws_size,
                              hipStream_t stream) {
    const float* x     = (const float*)d_in[0];   // [4,2048,1024]
    const float* w_qkv = (const float*)d_in[1];   // [1024,3072]
    const float* w_out = (const float*)d_in[2];   // [1024,1024]

    unsigned short* x_bf   = (unsigned short*)d_ws;                  // 8192*1024
    unsigned short* wqkvT  = x_bf   + (size_t)MROWS * DIMM;          // 3072*1024
    unsigned short* woutT  = wqkvT  + (size_t)3 * DIMM * DIMM;       // 1024*1024
    unsigned short* qkv_bf = woutT  + (size_t)DIMM * DIMM;           // 8192*3072
    unsigned short* aout   = qkv_bf + (size_t)MROWS * 3 * DIMM;      // 8192*1024
    unsigned short* vt     = x_bf;   // x_bf dead after QKV GEMM; alias it

    // 1. converts / transposes
    k_conv_bf16<<<(MROWS * DIMM / 4 + 255) / 256, 256, 0, stream>>>(x, x_bf, MROWS * DIMM / 4);
    dim3 g1(3 * DIMM / 32, DIMM / 32);
    k_transpose<<<g1, 256, 0, stream>>>(w_qkv, wqkvT, DIMM, 3 * DIMM);
    dim3 g2(DIMM / 32, DIMM / 32);
    k_transpose<<<g2, 256, 0, stream>>>(w_out, woutT, DIMM, DIMM);

    // 2. QKV projection (Q third pre-scaled by 0.125): -> bf16 [8192,3072]
    k_gemm_bt<1, 1><<<(MROWS / 128) * (3 * DIMM / 128), 256, 0, stream>>>(
        x_bf, wqkvT, qkv_bf, MROWS, 3 * DIMM, DIMM);

    // 3. per-head V^T (overwrites x_bf region)
    k_transpose_v<<<64 * 32, 256, 0, stream>>>(qkv_bf, vt);

    // 4. causal flash attention (sequential chunk pairing) -> bf16 [8192,1024]
    k_attn8<<<NB * NH * 8, 256, 0, stream>>>(qkv_bf, vt, aout);

    // 5. output projection: [8192,1024] x [1024,1024] -> fp32 d_out
    k_gemm_bt<0, 0><<<(MROWS / 128) * (DIMM / 128), 256, 0, stream>>>(
        aout, woutT, d_out, MROWS, DIMM, DIMM);
}

// Round 9
// 249.135 us; speedup vs baseline: 1.3860x; 1.0038x over previous
//
#include <hip/hip_runtime.h>
#include <hip/hip_bf16.h>
#include <stdint.h>

// Problem constants
#define SEQ  2048
#define DIMM 1024
#define NH   16
#define DH   64
#define NB   4
#define MROWS (NB*SEQ)   // 8192

typedef __attribute__((ext_vector_type(8))) short bf16x8;
typedef __attribute__((ext_vector_type(4))) float f32x4;
typedef __attribute__((ext_vector_type(16))) float f32x16;

__device__ __forceinline__ unsigned short f2bf(float f) {
    union { float f; uint32_t u; } c; c.f = f;
    uint32_t r = c.u + 0x7fff + ((c.u >> 16) & 1);
    return (unsigned short)(r >> 16);
}

__device__ __forceinline__ void gload_lds16(const void* g, void* lds) {
    __builtin_amdgcn_global_load_lds(
        (const __attribute__((address_space(1))) unsigned int*)(g),
        (__attribute__((address_space(3))) unsigned int*)(lds),
        16, 0, 0);
}

// ---------------- fp32 -> bf16 elementwise convert (vectorized) -------------
__global__ __launch_bounds__(256) void k_conv_bf16(const float* __restrict__ in,
                                                   unsigned short* __restrict__ out,
                                                   int n4) {
    int i = blockIdx.x * 256 + threadIdx.x;
    if (i >= n4) return;
    float4 v = ((const float4*)in)[i];
    ushort4 o;
    o.x = f2bf(v.x); o.y = f2bf(v.y); o.z = f2bf(v.z); o.w = f2bf(v.w);
    ((ushort4*)out)[i] = o;
}

// ------------- W [K][N] fp32  ->  Wt [N][K] bf16 (tiled transpose) ----------
__global__ __launch_bounds__(256) void k_transpose(const float* __restrict__ W,
                                                   unsigned short* __restrict__ Wt,
                                                   int K, int N) {
    __shared__ unsigned short tile[32][33];
    int tn = blockIdx.x, tk = blockIdx.y;
    int lx = threadIdx.x & 31, ly = threadIdx.x >> 5;  // 32 x 8
    #pragma unroll
    for (int i = 0; i < 32; i += 8) {
        int k = tk * 32 + ly + i;
        int n = tn * 32 + lx;
        tile[ly + i][lx] = f2bf(W[(size_t)k * N + n]);
    }
    __syncthreads();
    int k2 = tk * 32 + lx;
    #pragma unroll
    for (int i = 0; i < 32; i += 8) {
        int n2 = tn * 32 + ly + i;
        Wt[(size_t)n2 * K + k2] = tile[lx][ly + i];
    }
}

// ---- V columns of qkv  ->  vt[bh][d=64][n=2048] bf16 (per-head V^T) --------
__global__ __launch_bounds__(256) void k_transpose_v(const unsigned short* __restrict__ qkv,
                                                     unsigned short* __restrict__ vt) {
    __shared__ unsigned short tile[64 * 72];
    const int nt = blockIdx.x & 31;      // kv tile of 64
    const int bh = blockIdx.x >> 5;      // 0..63
    const int b = bh >> 4, h = bh & 15;
    const int n0 = nt * 64;
    const int t = threadIdx.x;

    #pragma unroll
    for (int i = 0; i < 2; ++i) {
        int c = t + 256 * i;
        int kv = c >> 3, d0 = (c & 7) * 8;
        bf16x8 v = *(const bf16x8*)(qkv + (size_t)(b * SEQ + n0 + kv) * 3072 + 2048 + h * 64 + d0);
        *(bf16x8*)&tile[kv * 72 + d0] = v;
    }
    __syncthreads();
    #pragma unroll
    for (int i = 0; i < 2; ++i) {
        int c = t + 256 * i;
        int d = c >> 3, k0 = (c & 7) * 8;
        bf16x8 o;
        #pragma unroll
        for (int e = 0; e < 8; ++e)
            ((unsigned short*)&o)[e] = tile[(k0 + e) * 72 + d];
        *(bf16x8*)(vt + (size_t)(bh * 64 + d) * SEQ + n0 + k0) = o;
    }
}

// --------- C[M][N] = A[M][K] * Bt[N][K]^T   (bf16 in, fp32/bf16 out) --------
// SCALE_Q: multiply output cols < 1024 (the Q third of QKV) by 0.125 (exact).
template<int OUT_BF16, int SCALE_Q>
__global__ __launch_bounds__(256) void k_gemm_bt(const unsigned short* __restrict__ A,
                                                 const unsigned short* __restrict__ Bt,
                                                 void* __restrict__ Cv,
                                                 int M, int N_, int K) {
    constexpr int BM = 128, BN = 128, BK = 32;
    __shared__ unsigned short lA[BM * BK];
    __shared__ unsigned short lB[BN * BK];
    const int ntile = N_ / BN;
    const int tm = blockIdx.x / ntile;
    const int tn = blockIdx.x % ntile;
    const int t = threadIdx.x;
    const int w = t >> 6, l = t & 63;
    const int wr = w >> 1, wc = w & 1;

    const unsigned short* Abase = A + (size_t)tm * BM * K;
    const unsigned short* Bbase = Bt + (size_t)tn * BN * K;

    f32x4 acc[4][4] = {};

    for (int k0 = 0; k0 < K; k0 += BK) {
        __syncthreads();
        #pragma unroll
        for (int i = 0; i < 2; ++i) {
            int offL = (i * 4 + w) * 1024 + l * 16;
            int row = offL >> 6;
            int kb  = offL & 63;
            gload_lds16((const char*)(Abase + (size_t)row * K + k0) + kb,
                        (char*)lA + (i * 4 + w) * 1024);
            gload_lds16((const char*)(Bbase + (size_t)row * K + k0) + kb,
                        (char*)lB + (i * 4 + w) * 1024);
        }
        __syncthreads();

        bf16x8 af[4], bfv[4];
        #pragma unroll
        for (int i = 0; i < 4; ++i)
            af[i] = *(const bf16x8*)&lA[(wr * 64 + i * 16 + (l & 15)) * BK + (l >> 4) * 8];
        #pragma unroll
        for (int j = 0; j < 4; ++j)
            bfv[j] = *(const bf16x8*)&lB[(wc * 64 + j * 16 + (l & 15)) * BK + (l >> 4) * 8];
        #pragma unroll
        for (int i = 0; i < 4; ++i)
            #pragma unroll
            for (int j = 0; j < 4; ++j)
                acc[i][j] = __builtin_amdgcn_mfma_f32_16x16x32_bf16(af[i], bfv[j], acc[i][j], 0, 0, 0);
    }

    const float cs = (SCALE_Q && tn < DIMM / BN) ? 0.125f : 1.0f;
    float* Cf = (float*)Cv;
    unsigned short* Cb = (unsigned short*)Cv;
    const int row0 = tm * BM + wr * 64 + (l >> 4) * 4;
    const int col0 = tn * BN + wc * 64 + (l & 15);
    #pragma unroll
    for (int i = 0; i < 4; ++i)
        #pragma unroll
        for (int j = 0; j < 4; ++j)
            #pragma unroll
            for (int r = 0; r < 4; ++r) {
                size_t idx = (size_t)(row0 + i * 16 + r) * N_ + (col0 + j * 16);
                if (OUT_BF16) Cb[idx] = f2bf(acc[i][j][r] * cs);
                else          Cf[idx] = acc[i][j][r];
            }
}

// -- causal flash attention (v9: fully in-register, O^T accumulation) --------
// Swapped QK^T: lane owns q-row l&31. P->bf16 via v_cvt_pk_bf16_f32 +
// v_permlane32_swap (bit-verified equivalent to the LDS path in R3/R4).
// PV computed as mfma(V^T, P) -> accumulates O^T (rows=d, cols=q=own lane):
// rescale and 1/l use the lane's OWN factors - zero shfl, zero LDS.
// Sequential chunk pairing: heavy (15-p) then light (p); uniform ~34 tiles.
__global__ __launch_bounds__(256, 2) void k_attn9(const unsigned short* __restrict__ qkv,
                                                  const unsigned short* __restrict__ vt,
                                                  unsigned short* __restrict__ out) {
    // bijective XCD swizzle: 512 blocks = 8 XCD x 64; 8 consecutive bh per XCD
    const int wid = (blockIdx.x & 7) * 64 + (blockIdx.x >> 3);
    const int bh = wid >> 3;                  // 0..63
    const int pair = wid & 7;                 // 0..7
    const int b = bh >> 4, h = bh & 15;
    const int w = threadIdx.x >> 6, l = threadIdx.x & 63;
    const int l31 = l & 31, hi = l >> 5;

    const unsigned short* qp = qkv + (size_t)(b * SEQ) * 3072 + h * 64;
    const unsigned short* kp = qp + 1024;
    const unsigned short* vb = vt + (size_t)bh * 64 * SEQ;
    unsigned short* op = out + (size_t)(b * SEQ) * DIMM + h * 64;

    union U8 { uint32_t u[4]; bf16x8 v; };

    for (int ci = 0; ci < 2; ++ci) {
        const int chunk = ci ? pair : 15 - pair;       // heavy first, then light
        const int q0w = chunk * 128 + w * 32;          // wave's first q row
        const int qrow = q0w + l31;                    // this lane's q row
        const int nt = (q0w >> 6) + 1;                 // kv-tile trip count

        // Q as B-operand: col = l31 (q), k = m*16 + hi*8 + e  (pre-scaled 1/8)
        bf16x8 qf[4];
        #pragma unroll
        for (int m = 0; m < 4; ++m)
            qf[m] = *(const bf16x8*)(qp + (size_t)(q0w + l31) * 3072 + m * 16 + hi * 8);

        // O^T accumulators: accO0 rows d=crow(r,hi), accO1 rows d=32+crow; col q=l31
        f32x16 accO0 = {}, accO1 = {};
        float m_run = -INFINITY, l_run = 0.f;

        // K as A-operand: row kv = f*32 + l31, k = m*16 + hi*8 + e
        bf16x8 kf[2][4];
        #pragma unroll
        for (int f = 0; f < 2; ++f)
            #pragma unroll
            for (int m = 0; m < 4; ++m)
                kf[f][m] = *(const bf16x8*)(kp + (size_t)(f * 32 + l31) * 3072 + m * 16 + hi * 8);

        for (int kt = 0; kt < nt; ++kt) {
            const int kv0 = kt * 64;
            const bool msk = (kt == nt - 1);

            // QK^T swapped -> S^T: lane holds q=l31, kv = f*32 + crow(r,hi)
            f32x16 s0 = {}, s1 = {};
            __builtin_amdgcn_s_setprio(1);
            #pragma unroll
            for (int m = 0; m < 4; ++m) {
                s0 = __builtin_amdgcn_mfma_f32_32x32x16_bf16(kf[0][m], qf[m], s0, 0, 0, 0);
                s1 = __builtin_amdgcn_mfma_f32_32x32x16_bf16(kf[1][m], qf[m], s1, 0, 0, 0);
            }
            __builtin_amdgcn_s_setprio(0);

            // V^T as A-operand (row d = l31 / 32+l31), issued early
            bf16x8 vf0[4], vf1[4];
            #pragma unroll
            for (int m = 0; m < 4; ++m) {
                vf0[m] = *(const bf16x8*)(vb + (size_t)l31 * SEQ + kv0 + m * 16 + hi * 8);
                vf1[m] = *(const bf16x8*)(vb + (size_t)(32 + l31) * SEQ + kv0 + m * 16 + hi * 8);
            }
            // K prefetch for next tile (kf dead after QK^T above)
            const int kvn = (kt + 1 < nt) ? kv0 + 64 : kv0;
            #pragma unroll
            for (int f = 0; f < 2; ++f)
                #pragma unroll
                for (int m = 0; m < 4; ++m)
                    kf[f][m] = *(const bf16x8*)(kp + (size_t)(kvn + f * 32 + l31) * 3072 + m * 16 + hi * 8);

            // ---- in-lane online softmax (lane owns q row = l31) ----
            float tmax = -1e30f;
            #pragma unroll
            for (int r = 0; r < 16; ++r) {
                const int crow = (r & 3) + 8 * (r >> 2) + 4 * hi;
                float v0 = s0[r];
                float v1 = s1[r];
                if (msk) {
                    if (kv0 + crow > qrow)      v0 = -1e30f;
                    if (kv0 + 32 + crow > qrow) v1 = -1e30f;
                }
                s0[r] = v0; s1[r] = v1;
                tmax = fmaxf(tmax, fmaxf(v0, v1));
            }
            tmax = fmaxf(tmax, __shfl_xor(tmax, 32));      // other kv half
            const bool up = __any(tmax > m_run);
            const float mnew = fmaxf(m_run, tmax);
            const float fct = __expf(m_run - mnew);
            float ps = 0.f;
            #pragma unroll
            for (int r = 0; r < 16; ++r) {
                float p0 = __expf(s0[r] - mnew);
                float p1 = __expf(s1[r] - mnew);
                s0[r] = p0; s1[r] = p1;
                ps += p0 + p1;
            }
            ps += __shfl_xor(ps, 32);
            l_run = l_run * fct + ps;
            m_run = mnew;

            // ---- rescale O^T with the lane's OWN factor (col q = l31) ----
            if (up) {
                #pragma unroll
                for (int r = 0; r < 16; ++r) { accO0[r] *= fct; accO1[r] *= fct; }
            }

            // ---- P -> bf16 pack + permlane redistribution (in-register) ----
            // pw[i] = kv pair (crow(2i,hi), +1); permlane32_swap exchanges the
            // hi-half so each lane assembles P[kv = m*16 + hi*8 + 0..7][own q].
            uint32_t pw0[8], pw1[8];
            #pragma unroll
            for (int i = 0; i < 8; ++i) {
                asm("v_cvt_pk_bf16_f32 %0, %1, %2" : "=v"(pw0[i]) : "v"(s0[2*i]), "v"(s0[2*i+1]));
                asm("v_cvt_pk_bf16_f32 %0, %1, %2" : "=v"(pw1[i]) : "v"(s1[2*i]), "v"(s1[2*i+1]));
            }
            __builtin_amdgcn_s_setprio(1);
            #define PVCHUNK(PW, BASE, VF0, VF1) do {                                     \
                uint32_t a0 = PW[BASE+0], b0 = PW[BASE+2];                               \
                uint32_t a1 = PW[BASE+1], b1 = PW[BASE+3];                               \
                asm("v_permlane32_swap_b32 %0, %1" : "+v"(a0), "+v"(b0));                \
                asm("v_permlane32_swap_b32 %0, %1" : "+v"(a1), "+v"(b1));                \
                U8 pb; pb.u[0] = a0; pb.u[1] = a1; pb.u[2] = b0; pb.u[3] = b1;           \
                accO0 = __builtin_amdgcn_mfma_f32_32x32x16_bf16(VF0, pb.v, accO0, 0, 0, 0); \
                accO1 = __builtin_amdgcn_mfma_f32_32x32x16_bf16(VF1, pb.v, accO1, 0, 0, 0); \
            } while (0)
            PVCHUNK(pw0, 0, vf0[0], vf1[0]);
            PVCHUNK(pw0, 4, vf0[1], vf1[1]);
            PVCHUNK(pw1, 0, vf0[2], vf1[2]);
            PVCHUNK(pw1, 4, vf0[3], vf1[3]);
            #undef PVCHUNK
            __builtin_amdgcn_s_setprio(0);
        }

        // epilogue: lane holds O[q = q0w+l31][d = crow + {0,32}], own l_run.
        // d-runs of 4 (d = 8g + 4hi + j) -> pack to uint2, 8B stores.
        const float inv = 1.0f / l_run;
        unsigned short* orow = op + (size_t)(q0w + l31) * DIMM;
        #pragma unroll
        for (int g = 0; g < 4; ++g) {
            uint2 u0, u1;
            float a0 = accO0[4*g+0] * inv, a1 = accO0[4*g+1] * inv;
            float a2 = accO0[4*g+2] * inv, a3 = accO0[4*g+3] * inv;
            float c0 = accO1[4*g+0] * inv, c1 = accO1[4*g+1] * inv;
            float c2 = accO1[4*g+2] * inv, c3 = accO1[4*g+3] * inv;
            asm("v_cvt_pk_bf16_f32 %0, %1, %2" : "=v"(u0.x) : "v"(a0), "v"(a1));
            asm("v_cvt_pk_bf16_f32 %0, %1, %2" : "=v"(u0.y) : "v"(a2), "v"(a3));
            asm("v_cvt_pk_bf16_f32 %0, %1, %2" : "=v"(u1.x) : "v"(c0), "v"(c1));
            asm("v_cvt_pk_bf16_f32 %0, %1, %2" : "=v"(u1.y) : "v"(c2), "v"(c3));
            *(uint2*)(orow + 8*g + 4*hi)      = u0;   // d = 8g+4hi .. +3
            *(uint2*)(orow + 32 + 8*g + 4*hi) = u1;   // d = 32+8g+4hi .. +3
        }
    }
}

// ---------------------------------------------------------------------------
extern "C" void kernel_launch(void* const* d_in, const int* in_sizes, int n_in,
                              void* d_out, int out_size, void* d_ws, size_t ws_size,
                              hipStream_t stream) {
    const float* x     = (const float*)d_in[0];   // [4,2048,1024]
    const float* w_qkv = (const float*)d_in[1];   // [1024,3072]
    const float* w_out = (const float*)d_in[2];   // [1024,1024]

    unsigned short* x_bf   = (unsigned short*)d_ws;                  // 8192*1024
    unsigned short* wqkvT  = x_bf   + (size_t)MROWS * DIMM;          // 3072*1024
    unsigned short* woutT  = wqkvT  + (size_t)3 * DIMM * DIMM;       // 1024*1024
    unsigned short* qkv_bf = woutT  + (size_t)DIMM * DIMM;           // 8192*3072
    unsigned short* aout   = qkv_bf + (size_t)MROWS * 3 * DIMM;      // 8192*1024
    unsigned short* vt     = x_bf;   // x_bf dead after QKV GEMM; alias it

    // 1. converts / transposes
    k_conv_bf16<<<(MROWS * DIMM / 4 + 255) / 256, 256, 0, stream>>>(x, x_bf, MROWS * DIMM / 4);
    dim3 g1(3 * DIMM / 32, DIMM / 32);
    k_transpose<<<g1, 256, 0, stream>>>(w_qkv, wqkvT, DIMM, 3 * DIMM);
    dim3 g2(DIMM / 32, DIMM / 32);
    k_transpose<<<g2, 256, 0, stream>>>(w_out, woutT, DIMM, DIMM);

    // 2. QKV projection (Q third pre-scaled by 0.125): -> bf16 [8192,3072]
    k_gemm_bt<1, 1><<<(MROWS / 128) * (3 * DIMM / 128), 256, 0, stream>>>(
        x_bf, wqkvT, qkv_bf, MROWS, 3 * DIMM, DIMM);

    // 3. per-head V^T (overwrites x_bf region)
    k_transpose_v<<<64 * 32, 256, 0, stream>>>(qkv_bf, vt);

    // 4. causal flash attention (in-register, O^T) -> bf16 [8192,1024]
    k_attn9<<<NB * NH * 8, 256, 0, stream>>>(qkv_bf, vt, aout);

    // 5. output projection: [8192,1024] x [1024,1024] -> fp32 d_out
    k_gemm_bt<0, 0><<<(MROWS / 128) * (DIMM / 128), 256, 0, stream>>>(
        aout, woutT, d_out, MROWS, DIMM, DIMM);
}